// Round 2
// baseline (72.679 us; speedup 1.0000x reference)
//
#include <hip/hip_runtime.h>

#define B_DIM 64
#define S_LEN 2048
#define H_DIM 256
#define TWO_PI 6.283185307179586f

// Pass 1: per (b, split) partial reductions of S0 = sum_t x, C1 = sum_t x*cos,
// S1 = sum_t x*sin over the rows of this split.
// Block: 256 threads = 4 waves. Wave w handles rows t = base+w, step 4.
// Lane l covers h in [4l, 4l+4) via one float4 load (16B/lane, 1KB/wave).
__global__ __launch_bounds__(256) void k_partial(const float* __restrict__ x,
                                                 float* __restrict__ partials,
                                                 int rows_per_split) {
    const int b = blockIdx.x;
    const int split = blockIdx.y;
    const int tid = threadIdx.x;
    const int lane = tid & 63;
    const int wave = tid >> 6;
    const int h0 = lane * 4;

    float s0[4] = {0.f, 0.f, 0.f, 0.f};
    float c1[4] = {0.f, 0.f, 0.f, 0.f};
    float s1[4] = {0.f, 0.f, 0.f, 0.f};

    const int t_begin = split * rows_per_split;
    const int t_end = t_begin + rows_per_split;
    const float wfreq = TWO_PI / (float)S_LEN;

    for (int t = t_begin + wave; t < t_end; t += 4) {
        const float4 v = *reinterpret_cast<const float4*>(
            x + ((size_t)b * S_LEN + t) * H_DIM + h0);
        float sn, cs;
        __sincosf(wfreq * (float)t, &sn, &cs);
        s0[0] += v.x;      s0[1] += v.y;      s0[2] += v.z;      s0[3] += v.w;
        c1[0] += v.x * cs; c1[1] += v.y * cs; c1[2] += v.z * cs; c1[3] += v.w * cs;
        s1[0] += v.x * sn; s1[1] += v.y * sn; s1[2] += v.z * sn; s1[3] += v.w * sn;
    }

    __shared__ float red[4][3 * H_DIM];
#pragma unroll
    for (int j = 0; j < 4; ++j) {
        red[wave][0 * H_DIM + h0 + j] = s0[j];
        red[wave][1 * H_DIM + h0 + j] = c1[j];
        red[wave][2 * H_DIM + h0 + j] = s1[j];
    }
    __syncthreads();

    // 768 values (3 comps x 256 h); each of 256 threads reduces 3 across 4 waves.
#pragma unroll
    for (int k = 0; k < 3; ++k) {
        const int v = tid + k * 256;
        const float acc = red[0][v] + red[1][v] + red[2][v] + red[3][v];
        partials[((size_t)(split * B_DIM + b)) * (3 * H_DIM) + v] = acc;
    }
}

// Pass 2: reduce the nsplit partials -> sums[b][3*256]
__global__ __launch_bounds__(256) void k_reduce(const float* __restrict__ partials,
                                                float* __restrict__ sums,
                                                int nsplit) {
    const int j = blockIdx.x * 256 + threadIdx.x;  // < B*768
    float acc = 0.f;
    for (int s = 0; s < nsplit; ++s)
        acc += partials[(size_t)s * (B_DIM * 3 * H_DIM) + j];
    sums[j] = acc;
}

// Pass 3: fused low-pass reconstruction + residual + LayerNorm.
// Block: 256 threads = 4 waves; block covers 16 rows (4 rows per wave).
// Lane l handles h in [4l, 4l+4) via float4.
#define ROWS_PER_BLOCK 16
__global__ __launch_bounds__(256) void k_final(const float* __restrict__ x,
                                               const float* __restrict__ sums,
                                               const float* __restrict__ sqrt_beta,
                                               const float* __restrict__ lnw,
                                               const float* __restrict__ lnb,
                                               float* __restrict__ out) {
    const int blocks_per_b = S_LEN / ROWS_PER_BLOCK;
    const int b = blockIdx.x / blocks_per_b;
    const int tchunk = blockIdx.x % blocks_per_b;
    const int tid = threadIdx.x;
    const int lane = tid & 63;
    const int wave = tid >> 6;

    __shared__ float sS0[H_DIM], sC1[H_DIM], sS1[H_DIM];
    __shared__ float sCA[H_DIM], sCB[H_DIM], sW[H_DIM], sBi[H_DIM];
    {
        const int h = tid;
        sS0[h] = sums[b * 768 + h];
        sC1[h] = sums[b * 768 + 256 + h];
        sS1[h] = sums[b * 768 + 512 + h];
        const float sb = sqrt_beta[h];
        const float b2 = sb * sb;
        sCA[h] = 1.f + b2;   // coefficient on x
        sCB[h] = 1.f - b2;   // coefficient on low_pass
        sW[h] = lnw[h];
        sBi[h] = lnb[h];
    }
    __syncthreads();

    const float invS = 1.f / (float)S_LEN;
    const float wfreq = TWO_PI / (float)S_LEN;
    const int h0 = lane * 4;

#pragma unroll
    for (int r = 0; r < ROWS_PER_BLOCK / 4; ++r) {
        const int t = tchunk * ROWS_PER_BLOCK + wave * (ROWS_PER_BLOCK / 4) + r;
        float sn, cs;
        __sincosf(wfreq * (float)t, &sn, &cs);

        const size_t base = ((size_t)b * S_LEN + t) * H_DIM + h0;
        const float4 v = *reinterpret_cast<const float4*>(x + base);
        const float xf[4] = {v.x, v.y, v.z, v.w};

        float y[4];
        float sum = 0.f, sumsq = 0.f;
#pragma unroll
        for (int j = 0; j < 4; ++j) {
            const int h = h0 + j;
            const float lp = invS * (sS0[h] + 2.f * (sC1[h] * cs + sS1[h] * sn));
            const float yy = sCB[h] * lp + sCA[h] * xf[j];
            y[j] = yy;
            sum += yy;
            sumsq += yy * yy;
        }
#pragma unroll
        for (int m = 1; m < 64; m <<= 1) {
            sum += __shfl_xor(sum, m, 64);
            sumsq += __shfl_xor(sumsq, m, 64);
        }
        const float mean = sum * (1.f / (float)H_DIM);
        const float var = sumsq * (1.f / (float)H_DIM) - mean * mean;
        const float rstd = rsqrtf(var + 1e-5f);

        float4 o;
        o.x = (y[0] - mean) * rstd * sW[h0 + 0] + sBi[h0 + 0];
        o.y = (y[1] - mean) * rstd * sW[h0 + 1] + sBi[h0 + 1];
        o.z = (y[2] - mean) * rstd * sW[h0 + 2] + sBi[h0 + 2];
        o.w = (y[3] - mean) * rstd * sW[h0 + 3] + sBi[h0 + 3];
        *reinterpret_cast<float4*>(out + base) = o;
    }
}

extern "C" void kernel_launch(void* const* d_in, const int* in_sizes, int n_in,
                              void* d_out, int out_size, void* d_ws, size_t ws_size,
                              hipStream_t stream) {
    const float* x  = (const float*)d_in[0];
    const float* sb = (const float*)d_in[1];
    const float* w  = (const float*)d_in[2];
    const float* bi = (const float*)d_in[3];
    float* out = (float*)d_out;

    // workspace: partials [nsplit][B][3*H] fp32 + sums [B][3*H] fp32
    int nsplit = 16;
    while (nsplit > 1 &&
           ((size_t)(nsplit + 1) * B_DIM * 3 * H_DIM * sizeof(float)) > ws_size)
        nsplit >>= 1;
    float* partials = (float*)d_ws;
    float* sums = partials + (size_t)nsplit * B_DIM * 3 * H_DIM;

    k_partial<<<dim3(B_DIM, nsplit), 256, 0, stream>>>(x, partials, S_LEN / nsplit);
    k_reduce<<<(B_DIM * 3 * H_DIM) / 256, 256, 0, stream>>>(partials, sums, nsplit);
    k_final<<<B_DIM * (S_LEN / ROWS_PER_BLOCK), 256, 0, stream>>>(x, sums, sb, w, bi, out);
}